// Round 1
// baseline (884.410 us; speedup 1.0000x reference)
//
#include <hip/hip_runtime.h>

#define N_NODES 100000
#define N_EDGES 3200000

// ---------------------------------------------------------------------------
// GCN 2-layer, algebraically refactored:
//   out = Â relu( (Â x) W1^T + b1 ) W2^T + b2   where  Â = D^-1/2 (A+I) D^-1/2
// Aggregation commutes with the linear maps, so both aggregations are done in
// the 2-dim feature space (x before W1; y = h@W2^T before the 2nd aggregation).
// The 64-dim hidden layer never touches memory.
// ---------------------------------------------------------------------------

__global__ __launch_bounds__(256) void k_init_deg(float* deg, int n) {
    int i = blockIdx.x * blockDim.x + threadIdx.x;
    if (i < n) deg[i] = 1.0f;  // self-loop
}

__global__ __launch_bounds__(256) void k_count_deg(const int* __restrict__ dst,
                                                   float* deg, int e) {
    int i = blockIdx.x * blockDim.x + threadIdx.x;
    if (i < e) atomicAdd(&deg[dst[i]], 1.0f);
}

// dinv = rsqrt(deg) (in-place over deg); u = dinv * x; acc1 = u (self term)
__global__ __launch_bounds__(256) void k_prep1(const float* __restrict__ x,
                                               float* dinv, float2* u,
                                               float2* acc1, int n) {
    int i = blockIdx.x * blockDim.x + threadIdx.x;
    if (i < n) {
        float d = rsqrtf(dinv[i]);   // dinv currently holds deg (>= 1 always)
        dinv[i] = d;
        float2 xv = ((const float2*)x)[i];
        float2 uu = make_float2(d * xv.x, d * xv.y);
        u[i] = uu;
        acc1[i] = uu;
    }
}

// acc[dst] += u[src]  (2 floats per edge)
__global__ __launch_bounds__(256) void k_scatter(const int* __restrict__ src,
                                                 const int* __restrict__ dst,
                                                 const float2* __restrict__ u,
                                                 float2* acc, int e) {
    int i = blockIdx.x * blockDim.x + threadIdx.x;
    if (i < e) {
        int s = src[i];
        int d = dst[i];
        float2 uu = u[s];
        atomicAdd(&acc[d].x, uu.x);
        atomicAdd(&acc[d].y, uu.y);
    }
}

// per node: a = dinv*acc1;  h = relu(W1 a + b1) (64, registers only);
// y = W2 h;  v = dinv*y;  acc2 = v (self term)
__global__ __launch_bounds__(256) void k_mlp(const float* __restrict__ dinv,
                                             const float2* __restrict__ acc1,
                                             const float* __restrict__ W1,
                                             const float* __restrict__ b1,
                                             const float* __restrict__ W2,
                                             const float* __restrict__ b2,
                                             float2* v, float2* acc2, int n) {
    __shared__ float sW1[128], sb1[64], sW2[128];
    for (int t = threadIdx.x; t < 128; t += blockDim.x) {
        sW1[t] = W1[t];
        sW2[t] = W2[t];
    }
    for (int t = threadIdx.x; t < 64; t += blockDim.x) sb1[t] = b1[t];
    __syncthreads();

    int i = blockIdx.x * blockDim.x + threadIdx.x;
    if (i < n) {
        float d = dinv[i];
        float2 a = acc1[i];
        a.x *= d; a.y *= d;
        float y0 = 0.0f, y1 = 0.0f;
#pragma unroll
        for (int j = 0; j < 64; ++j) {
            float h = fmaxf(fmaf(sW1[2 * j], a.x,
                            fmaf(sW1[2 * j + 1], a.y, sb1[j])), 0.0f);
            y0 = fmaf(sW2[j], h, y0);        // W2[0][j]
            y1 = fmaf(sW2[64 + j], h, y1);   // W2[1][j]
        }
        float2 vv = make_float2(d * y0, d * y1);
        v[i] = vv;
        acc2[i] = vv;
    }
}

__global__ __launch_bounds__(256) void k_out(const float* __restrict__ dinv,
                                             const float2* __restrict__ acc2,
                                             const float* __restrict__ b2,
                                             float2* out, int n) {
    int i = blockIdx.x * blockDim.x + threadIdx.x;
    if (i < n) {
        float d = dinv[i];
        float2 t = acc2[i];
        out[i] = make_float2(fmaf(d, t.x, b2[0]), fmaf(d, t.y, b2[1]));
    }
}

extern "C" void kernel_launch(void* const* d_in, const int* in_sizes, int n_in,
                              void* d_out, int out_size, void* d_ws, size_t ws_size,
                              hipStream_t stream) {
    const float* x  = (const float*)d_in[0];
    const int* ei   = (const int*)d_in[1];      // [2, E] row-major: src then dst
    const float* W1 = (const float*)d_in[2];    // [64,2]
    const float* b1 = (const float*)d_in[3];    // [64]
    const float* W2 = (const float*)d_in[4];    // [2,64]
    const float* b2 = (const float*)d_in[5];    // [2]

    const int* src = ei;
    const int* dst = ei + N_EDGES;

    // workspace layout (floats): dinv[N] | u[2N] | acc1[2N] | v[2N] | acc2[2N]
    float* ws    = (float*)d_ws;
    float*  dinv = ws;                       // holds deg, then dinv (in place)
    float2* u    = (float2*)(ws + N_NODES);
    float2* acc1 = (float2*)(ws + 3 * N_NODES);
    float2* v    = (float2*)(ws + 5 * N_NODES);
    float2* acc2 = (float2*)(ws + 7 * N_NODES);

    const int B = 256;
    const int gN = (N_NODES + B - 1) / B;
    const int gE = (N_EDGES + B - 1) / B;

    k_init_deg<<<gN, B, 0, stream>>>(dinv, N_NODES);
    k_count_deg<<<gE, B, 0, stream>>>(dst, dinv, N_EDGES);
    k_prep1<<<gN, B, 0, stream>>>(x, dinv, u, acc1, N_NODES);
    k_scatter<<<gE, B, 0, stream>>>(src, dst, u, acc1, N_EDGES);
    k_mlp<<<gN, B, 0, stream>>>(dinv, acc1, W1, b1, W2, b2, v, acc2, N_NODES);
    k_scatter<<<gE, B, 0, stream>>>(src, dst, v, acc2, N_EDGES);
    k_out<<<gN, B, 0, stream>>>(dinv, acc2, b2, (float2*)d_out, N_NODES);
}

// Round 2
// 227.167 us; speedup vs baseline: 3.8932x; 3.8932x over previous
//
#include <hip/hip_runtime.h>

#define N_NODES 100000
#define SHIFT 6
#define BNODES 64                                   // nodes per bucket
#define NB ((N_NODES + BNODES - 1) / BNODES)        // 1563 buckets
#define PBLOCKS 256
#define PTHREADS 512

// ---------------------------------------------------------------------------
// GCN 2-layer, algebraically refactored (aggregation in 2-dim feature space):
//   out = Â relu( (Â x) W1^T + b1 ) W2^T + b2 ,  Â = D^-1/2 (A+I) D^-1/2
// R1 showed scattered global fp32 atomics cost 32B write-through each
// (200 MB/scatter). This version counting-sorts edges by dst bucket once,
// then aggregates via LDS atomics per 64-node tile — no global atomics on
// the hot path.
// ---------------------------------------------------------------------------

__global__ __launch_bounds__(256) void k_zero(int* counts) {
    int i = blockIdx.x * blockDim.x + threadIdx.x;
    if (i < NB) counts[i] = 0;
}

__global__ __launch_bounds__(PTHREADS) void k_hist(const int* __restrict__ dst,
                                                   int* counts, int e) {
    __shared__ int h[NB];
    for (int i = threadIdx.x; i < NB; i += PTHREADS) h[i] = 0;
    __syncthreads();
    int chunk = (e + gridDim.x - 1) / gridDim.x;
    int s = blockIdx.x * chunk;
    int en = s + chunk; if (en > e) en = e;
    for (int i = s + threadIdx.x; i < en; i += PTHREADS)
        atomicAdd(&h[dst[i] >> SHIFT], 1);
    __syncthreads();
    for (int i = threadIdx.x; i < NB; i += PTHREADS)
        if (h[i]) atomicAdd(&counts[i], h[i]);
}

// single block, 1024 threads, exclusive scan of NB (<=2048) counts
__global__ __launch_bounds__(1024) void k_scan(const int* __restrict__ counts,
                                               int* offsets, int* claim) {
    __shared__ int buf[1024];
    int t = threadIdx.x;
    int i0 = 2 * t, i1 = 2 * t + 1;
    int a0 = (i0 < NB) ? counts[i0] : 0;
    int a1 = (i1 < NB) ? counts[i1] : 0;
    int s = a0 + a1;
    buf[t] = s;
    __syncthreads();
    for (int off = 1; off < 1024; off <<= 1) {
        int v = (t >= off) ? buf[t - off] : 0;
        __syncthreads();
        buf[t] += v;
        __syncthreads();
    }
    int excl = buf[t] - s;  // exclusive prefix of this pair
    if (i0 <= NB) { offsets[i0] = excl;      claim[i0] = excl; }
    if (i1 <= NB) { offsets[i1] = excl + a0; claim[i1] = excl + a0; }
}

__global__ __launch_bounds__(PTHREADS) void k_place(const int* __restrict__ src,
                                                    const int* __restrict__ dst,
                                                    int* claim, int* sorted, int e) {
    __shared__ int h[NB];
    __shared__ int base[NB];
    for (int i = threadIdx.x; i < NB; i += PTHREADS) h[i] = 0;
    __syncthreads();
    int chunk = (e + gridDim.x - 1) / gridDim.x;
    int s0 = blockIdx.x * chunk;
    int en = s0 + chunk; if (en > e) en = e;
    for (int i = s0 + threadIdx.x; i < en; i += PTHREADS)
        atomicAdd(&h[dst[i] >> SHIFT], 1);
    __syncthreads();
    for (int i = threadIdx.x; i < NB; i += PTHREADS) {
        int c = h[i];
        base[i] = c ? atomicAdd(&claim[i], c) : 0;
        h[i] = 0;  // reuse as local rank counter
    }
    __syncthreads();
    for (int i = s0 + threadIdx.x; i < en; i += PTHREADS) {
        int d = dst[i];
        int bin = d >> SHIFT;
        int r = atomicAdd(&h[bin], 1);
        sorted[base[bin] + r] = src[i] | ((d & (BNODES - 1)) << 17);
    }
}

// per bucket: degree from sorted edges (LDS), dinv = rsqrt(deg+1), u = dinv*x
__global__ __launch_bounds__(256) void k_prep(const int* __restrict__ offsets,
                                              const int* __restrict__ sorted,
                                              const float* __restrict__ x,
                                              float* dinv, float2* u) {
    __shared__ int cnt[BNODES];
    int t = threadIdx.x;
    if (t < BNODES) cnt[t] = 1;  // self-loop
    __syncthreads();
    int b = blockIdx.x;
    int s = offsets[b], en = offsets[b + 1];
    for (int i = s + t; i < en; i += 256)
        atomicAdd(&cnt[sorted[i] >> 17], 1);
    __syncthreads();
    if (t < BNODES) {
        int node = b * BNODES + t;
        if (node < N_NODES) {
            float d = rsqrtf((float)cnt[t]);
            dinv[node] = d;
            float2 xv = ((const float2*)x)[node];
            u[node] = make_float2(d * xv.x, d * xv.y);
        }
    }
}

// layer-1 aggregation (LDS) fused with the entire 64-dim MLP:
// a = dinv*(sum + u_self); h = relu(W1 a + b1); v = dinv * (W2 h)
__global__ __launch_bounds__(256) void k_agg1(const int* __restrict__ offsets,
                                              const int* __restrict__ sorted,
                                              const float2* __restrict__ u,
                                              const float* __restrict__ dinv,
                                              const float* __restrict__ W1,
                                              const float* __restrict__ b1,
                                              const float* __restrict__ W2,
                                              float2* v) {
    __shared__ float ax[BNODES], ay[BNODES];
    __shared__ float sW1[128], sb1[64], sW2[128];
    int t = threadIdx.x;
    if (t < BNODES) { ax[t] = 0.0f; ay[t] = 0.0f; }
    if (t >= 64 && t < 192) { sW1[t - 64] = W1[t - 64]; sW2[t - 64] = W2[t - 64]; }
    else if (t < 64) sb1[t] = b1[t];
    __syncthreads();
    int b = blockIdx.x;
    int s = offsets[b], en = offsets[b + 1];
    for (int i = s + t; i < en; i += 256) {
        int p = sorted[i];
        float2 g = u[p & 0x1FFFF];
        int dl = p >> 17;
        atomicAdd(&ax[dl], g.x);
        atomicAdd(&ay[dl], g.y);
    }
    __syncthreads();
    if (t < BNODES) {
        int node = b * BNODES + t;
        if (node < N_NODES) {
            float dv = dinv[node];
            float2 un = u[node];
            float a0 = dv * (ax[t] + un.x);
            float a1 = dv * (ay[t] + un.y);
            float y0 = 0.0f, y1 = 0.0f;
#pragma unroll
            for (int j = 0; j < 64; ++j) {
                float h = fmaxf(fmaf(sW1[2 * j], a0,
                                fmaf(sW1[2 * j + 1], a1, sb1[j])), 0.0f);
                y0 = fmaf(sW2[j], h, y0);       // W2[0][j]
                y1 = fmaf(sW2[64 + j], h, y1);  // W2[1][j]
            }
            v[node] = make_float2(dv * y0, dv * y1);
        }
    }
}

// layer-2 aggregation fused with bias: out = dinv*(sum + v_self) + b2
__global__ __launch_bounds__(256) void k_agg2(const int* __restrict__ offsets,
                                              const int* __restrict__ sorted,
                                              const float2* __restrict__ v,
                                              const float* __restrict__ dinv,
                                              const float* __restrict__ b2,
                                              float2* out) {
    __shared__ float ax[BNODES], ay[BNODES];
    int t = threadIdx.x;
    if (t < BNODES) { ax[t] = 0.0f; ay[t] = 0.0f; }
    __syncthreads();
    int b = blockIdx.x;
    int s = offsets[b], en = offsets[b + 1];
    for (int i = s + t; i < en; i += 256) {
        int p = sorted[i];
        float2 g = v[p & 0x1FFFF];
        int dl = p >> 17;
        atomicAdd(&ax[dl], g.x);
        atomicAdd(&ay[dl], g.y);
    }
    __syncthreads();
    if (t < BNODES) {
        int node = b * BNODES + t;
        if (node < N_NODES) {
            float dv = dinv[node];
            float2 vn = v[node];
            out[node] = make_float2(fmaf(dv, ax[t] + vn.x, b2[0]),
                                    fmaf(dv, ay[t] + vn.y, b2[1]));
        }
    }
}

extern "C" void kernel_launch(void* const* d_in, const int* in_sizes, int n_in,
                              void* d_out, int out_size, void* d_ws, size_t ws_size,
                              hipStream_t stream) {
    const float* x  = (const float*)d_in[0];
    const int* ei   = (const int*)d_in[1];   // [2,E]: src row then dst row
    const float* W1 = (const float*)d_in[2];
    const float* b1 = (const float*)d_in[3];
    const float* W2 = (const float*)d_in[4];
    const float* b2 = (const float*)d_in[5];

    const int e = in_sizes[1] / 2;
    const int* src = ei;
    const int* dst = ei + e;

    // ws layout (ints/floats, 4B units):
    // counts[NB] | offsets[NB+1] | claim[NB+1] | sorted[E] | dinv[N] | u[2N] | v[2N]
    int* ws      = (int*)d_ws;
    int* counts  = ws;
    int* offsets = counts + NB;
    int* claim   = offsets + NB + 1;
    int* sorted  = claim + NB + 1;
    float* dinv  = (float*)(sorted + e);
    float2* u    = (float2*)(dinv + N_NODES);
    float2* v    = u + N_NODES;

    k_zero <<<(NB + 255) / 256, 256, 0, stream>>>(counts);
    k_hist <<<PBLOCKS, PTHREADS, 0, stream>>>(dst, counts, e);
    k_scan <<<1, 1024, 0, stream>>>(counts, offsets, claim);
    k_place<<<PBLOCKS, PTHREADS, 0, stream>>>(src, dst, claim, sorted, e);
    k_prep <<<NB, 256, 0, stream>>>(offsets, sorted, x, dinv, u);
    k_agg1 <<<NB, 256, 0, stream>>>(offsets, sorted, u, dinv, W1, b1, W2, v);
    k_agg2 <<<NB, 256, 0, stream>>>(offsets, sorted, v, dinv, b2, (float2*)d_out);
}

// Round 3
// 217.931 us; speedup vs baseline: 4.0582x; 1.0424x over previous
//
#include <hip/hip_runtime.h>

#define N_NODES 100000
#define SHIFT 9
#define BNODES 512                                  // nodes per bucket
#define NB ((N_NODES + BNODES - 1) / BNODES)        // 196 buckets
#define PBLOCKS 256
#define PTHREADS 512
#define ATHREADS 1024

// ---------------------------------------------------------------------------
// GCN 2-layer, algebraically refactored (aggregation in 2-dim feature space):
//   out = Â relu( (Â x) W1^T + b1 ) W2^T + b2 ,  Â = D^-1/2 (A+I) D^-1/2
// Edges counting-sorted by 512-node dst bucket (coarse buckets => placement
// writes are ~256B contiguous runs per bin per block, no cache-line write
// amplification). Aggregation via LDS atomics per 512-node tile; the 64-dim
// hidden layer lives entirely in registers.
// ---------------------------------------------------------------------------

__global__ __launch_bounds__(256) void k_zero(int* counts) {
    int i = blockIdx.x * blockDim.x + threadIdx.x;
    if (i < NB) counts[i] = 0;
}

__global__ __launch_bounds__(PTHREADS) void k_hist(const int* __restrict__ dst,
                                                   int* counts, int e) {
    __shared__ int h[NB];
    for (int i = threadIdx.x; i < NB; i += PTHREADS) h[i] = 0;
    __syncthreads();
    int chunk = (e + gridDim.x - 1) / gridDim.x;
    int s = blockIdx.x * chunk;
    int en = s + chunk; if (en > e) en = e;
    for (int i = s + threadIdx.x; i < en; i += PTHREADS)
        atomicAdd(&h[dst[i] >> SHIFT], 1);
    __syncthreads();
    for (int i = threadIdx.x; i < NB; i += PTHREADS)
        if (h[i]) atomicAdd(&counts[i], h[i]);
}

// single block, 256 threads: exclusive scan of NB (<=256) counts
__global__ __launch_bounds__(256) void k_scan(const int* __restrict__ counts,
                                              int* offsets, int* claim) {
    __shared__ int buf[256];
    int t = threadIdx.x;
    int v = (t < NB) ? counts[t] : 0;
    buf[t] = v;
    __syncthreads();
    for (int off = 1; off < 256; off <<= 1) {
        int w = (t >= off) ? buf[t - off] : 0;
        __syncthreads();
        buf[t] += w;
        __syncthreads();
    }
    if (t < NB) { offsets[t + 1] = buf[t]; claim[t] = buf[t] - v; }
    if (t == 0) offsets[0] = 0;
}

__global__ __launch_bounds__(PTHREADS) void k_place(const int* __restrict__ src,
                                                    const int* __restrict__ dst,
                                                    int* claim, int* sorted, int e) {
    __shared__ int h[NB];
    __shared__ int base[NB];
    for (int i = threadIdx.x; i < NB; i += PTHREADS) h[i] = 0;
    __syncthreads();
    int chunk = (e + gridDim.x - 1) / gridDim.x;
    int s0 = blockIdx.x * chunk;
    int en = s0 + chunk; if (en > e) en = e;
    for (int i = s0 + threadIdx.x; i < en; i += PTHREADS)
        atomicAdd(&h[dst[i] >> SHIFT], 1);
    __syncthreads();
    for (int i = threadIdx.x; i < NB; i += PTHREADS) {
        int c = h[i];
        base[i] = c ? atomicAdd(&claim[i], c) : 0;
        h[i] = 0;  // reuse as local rank counter
    }
    __syncthreads();
    for (int i = s0 + threadIdx.x; i < en; i += PTHREADS) {
        int d = dst[i];
        int bin = d >> SHIFT;
        int r = atomicAdd(&h[bin], 1);
        sorted[base[bin] + r] = src[i] | ((d & (BNODES - 1)) << 17);
    }
}

// per bucket: degree from sorted edges (LDS), dinv = rsqrt(deg+1), u = dinv*x
__global__ __launch_bounds__(ATHREADS) void k_prep(const int* __restrict__ offsets,
                                                   const int* __restrict__ sorted,
                                                   const float* __restrict__ x,
                                                   float* dinv, float2* u) {
    __shared__ int cnt[BNODES];
    int t = threadIdx.x;
    if (t < BNODES) cnt[t] = 1;  // self-loop
    __syncthreads();
    int b = blockIdx.x;
    int s = offsets[b], en = offsets[b + 1];
    for (int i = s + t; i < en; i += ATHREADS)
        atomicAdd(&cnt[sorted[i] >> 17], 1);
    __syncthreads();
    if (t < BNODES) {
        int node = b * BNODES + t;
        if (node < N_NODES) {
            float d = rsqrtf((float)cnt[t]);
            dinv[node] = d;
            float2 xv = ((const float2*)x)[node];
            u[node] = make_float2(d * xv.x, d * xv.y);
        }
    }
}

// layer-1 aggregation (LDS) fused with the entire 64-dim MLP:
// a = dinv*(sum + u_self); h = relu(W1 a + b1); v = dinv * (W2 h)
__global__ __launch_bounds__(ATHREADS) void k_agg1(const int* __restrict__ offsets,
                                                   const int* __restrict__ sorted,
                                                   const float2* __restrict__ u,
                                                   const float* __restrict__ dinv,
                                                   const float* __restrict__ W1,
                                                   const float* __restrict__ b1,
                                                   const float* __restrict__ W2,
                                                   float2* v) {
    __shared__ float ax[BNODES], ay[BNODES];
    __shared__ float sW1[128], sb1[64], sW2[128];
    int t = threadIdx.x;
    if (t < BNODES) { ax[t] = 0.0f; ay[t] = 0.0f; }
    if (t >= 512 && t < 640) { sW1[t - 512] = W1[t - 512]; sW2[t - 512] = W2[t - 512]; }
    else if (t >= 640 && t < 704) sb1[t - 640] = b1[t - 640];
    __syncthreads();
    int b = blockIdx.x;
    int s = offsets[b], en = offsets[b + 1];
    for (int i = s + t; i < en; i += ATHREADS) {
        int p = sorted[i];
        float2 g = u[p & 0x1FFFF];
        int dl = p >> 17;
        atomicAdd(&ax[dl], g.x);
        atomicAdd(&ay[dl], g.y);
    }
    __syncthreads();
    if (t < BNODES) {
        int node = b * BNODES + t;
        if (node < N_NODES) {
            float dv = dinv[node];
            float2 un = u[node];
            float a0 = dv * (ax[t] + un.x);
            float a1 = dv * (ay[t] + un.y);
            float y0 = 0.0f, y1 = 0.0f;
#pragma unroll
            for (int j = 0; j < 64; ++j) {
                float h = fmaxf(fmaf(sW1[2 * j], a0,
                                fmaf(sW1[2 * j + 1], a1, sb1[j])), 0.0f);
                y0 = fmaf(sW2[j], h, y0);       // W2[0][j]
                y1 = fmaf(sW2[64 + j], h, y1);  // W2[1][j]
            }
            v[node] = make_float2(dv * y0, dv * y1);
        }
    }
}

// layer-2 aggregation fused with bias: out = dinv*(sum + v_self) + b2
__global__ __launch_bounds__(ATHREADS) void k_agg2(const int* __restrict__ offsets,
                                                   const int* __restrict__ sorted,
                                                   const float2* __restrict__ v,
                                                   const float* __restrict__ dinv,
                                                   const float* __restrict__ b2,
                                                   float2* out) {
    __shared__ float ax[BNODES], ay[BNODES];
    int t = threadIdx.x;
    if (t < BNODES) { ax[t] = 0.0f; ay[t] = 0.0f; }
    __syncthreads();
    int b = blockIdx.x;
    int s = offsets[b], en = offsets[b + 1];
    for (int i = s + t; i < en; i += ATHREADS) {
        int p = sorted[i];
        float2 g = v[p & 0x1FFFF];
        int dl = p >> 17;
        atomicAdd(&ax[dl], g.x);
        atomicAdd(&ay[dl], g.y);
    }
    __syncthreads();
    if (t < BNODES) {
        int node = b * BNODES + t;
        if (node < N_NODES) {
            float dv = dinv[node];
            float2 vn = v[node];
            out[node] = make_float2(fmaf(dv, ax[t] + vn.x, b2[0]),
                                    fmaf(dv, ay[t] + vn.y, b2[1]));
        }
    }
}

extern "C" void kernel_launch(void* const* d_in, const int* in_sizes, int n_in,
                              void* d_out, int out_size, void* d_ws, size_t ws_size,
                              hipStream_t stream) {
    const float* x  = (const float*)d_in[0];
    const int* ei   = (const int*)d_in[1];   // [2,E]: src row then dst row
    const float* W1 = (const float*)d_in[2];
    const float* b1 = (const float*)d_in[3];
    const float* W2 = (const float*)d_in[4];
    const float* b2 = (const float*)d_in[5];

    const int e = in_sizes[1] / 2;
    const int* src = ei;
    const int* dst = ei + e;

    // ws layout (4B units):
    // counts[NB] | offsets[NB+1] | claim[NB] | sorted[E] | dinv[N] | u[2N] | v[2N]
    int* ws      = (int*)d_ws;
    int* counts  = ws;
    int* offsets = counts + NB;
    int* claim   = offsets + NB + 1;
    int* sorted  = claim + NB;
    float* dinv  = (float*)(sorted + e);
    float2* u    = (float2*)(dinv + N_NODES);
    float2* v    = u + N_NODES;

    k_zero <<<1, 256, 0, stream>>>(counts);
    k_hist <<<PBLOCKS, PTHREADS, 0, stream>>>(dst, counts, e);
    k_scan <<<1, 256, 0, stream>>>(counts, offsets, claim);
    k_place<<<PBLOCKS, PTHREADS, 0, stream>>>(src, dst, claim, sorted, e);
    k_prep <<<NB, ATHREADS, 0, stream>>>(offsets, sorted, x, dinv, u);
    k_agg1 <<<NB, ATHREADS, 0, stream>>>(offsets, sorted, u, dinv, W1, b1, W2, v);
    k_agg2 <<<NB, ATHREADS, 0, stream>>>(offsets, sorted, v, dinv, b2, (float2*)d_out);
}

// Round 4
// 214.775 us; speedup vs baseline: 4.1179x; 1.0147x over previous
//
#include <hip/hip_runtime.h>

#define N_NODES 100000
#define SHIFT 9
#define BNODES 512                                  // nodes per dst bucket
#define NB ((N_NODES + BNODES - 1) / BNODES)        // 196 buckets
#define TRASH BNODES                                // LDS trash slot (512)
#define DUMMY (TRASH << 17)                         // pad record: src=0, dl=512
#define SPLIT 8                                     // edge-slice blocks per bucket
#define PBLOCKS 512
#define PTHREADS 512
#define EB 256                                      // edge-slice block size
#define NBK ((N_NODES + 255) / 256)                 // node-kernel blocks

// ---------------------------------------------------------------------------
// GCN 2-layer, algebraically refactored (aggregation in 2-dim feature space):
//   out = Â relu( (Â x) W1^T + b1 ) W2^T + b2 ,  Â = D^-1/2 (A+I) D^-1/2
// Edges counting-sorted by 512-node dst bucket. Each bucket's edges are
// processed by SPLIT blocks accumulating into LDS tiles; partial tiles flush
// with CONTIGUOUS global atomics (coalesced, no write amplification).
// Bucket edge counts padded to x4 so the hot loops read int4 (4-edge ILP).
// The 64-dim hidden layer lives entirely in registers of a node kernel.
// ---------------------------------------------------------------------------

__global__ __launch_bounds__(256) void k_init(int* counts, int* deg) {
    int i = blockIdx.x * 256 + threadIdx.x;
    if (i < NB) counts[i] = 0;
    if (i < N_NODES) deg[i] = 1;  // self-loop
}

__global__ __launch_bounds__(PTHREADS) void k_hist(const int* __restrict__ dst,
                                                   int* counts, int e) {
    __shared__ int h[NB];
    int t = threadIdx.x;
    for (int i = t; i < NB; i += PTHREADS) h[i] = 0;
    __syncthreads();
    int chunk = (((e + (int)gridDim.x - 1) / (int)gridDim.x) + 3) & ~3;
    int s0 = blockIdx.x * chunk;
    int en = s0 + chunk; if (en > e) en = e;
    if (s0 < e) {
        for (int i = s0 + 4 * t; i + 3 < en; i += 4 * PTHREADS) {
            int4 d4 = *(const int4*)(dst + i);
            atomicAdd(&h[d4.x >> SHIFT], 1);
            atomicAdd(&h[d4.y >> SHIFT], 1);
            atomicAdd(&h[d4.z >> SHIFT], 1);
            atomicAdd(&h[d4.w >> SHIFT], 1);
        }
        int tb = en & ~3;
        if (tb >= s0 && t < en - tb) atomicAdd(&h[dst[tb + t] >> SHIFT], 1);
    }
    __syncthreads();
    for (int i = t; i < NB; i += PTHREADS)
        if (h[i]) atomicAdd(&counts[i], h[i]);
}

// single block: exclusive scan of x4-padded counts; writes pad (dummy) records
__global__ __launch_bounds__(256) void k_scan(const int* __restrict__ counts,
                                              int* offsets, int* claim,
                                              int* sorted) {
    __shared__ int buf[256];
    int t = threadIdx.x;
    int c = (t < NB) ? counts[t] : 0;
    int pc = (c + 3) & ~3;
    buf[t] = pc;
    __syncthreads();
    for (int off = 1; off < 256; off <<= 1) {
        int w = (t >= off) ? buf[t - off] : 0;
        __syncthreads();
        buf[t] += w;
        __syncthreads();
    }
    if (t < NB) {
        int end = buf[t];
        int start = end - pc;
        offsets[t + 1] = end;
        claim[t] = start;
        for (int i = start + c; i < end; ++i) sorted[i] = DUMMY;
    }
    if (t == 0) offsets[0] = 0;
}

__global__ __launch_bounds__(PTHREADS) void k_place(const int* __restrict__ src,
                                                    const int* __restrict__ dst,
                                                    int* claim, int* sorted, int e) {
    __shared__ int h[NB];
    __shared__ int base[NB];
    int t = threadIdx.x;
    for (int i = t; i < NB; i += PTHREADS) h[i] = 0;
    __syncthreads();
    int chunk = (((e + (int)gridDim.x - 1) / (int)gridDim.x) + 3) & ~3;
    int s0 = blockIdx.x * chunk;
    int en = s0 + chunk; if (en > e) en = e;
    if (s0 < e) {
        for (int i = s0 + 4 * t; i + 3 < en; i += 4 * PTHREADS) {
            int4 d4 = *(const int4*)(dst + i);
            atomicAdd(&h[d4.x >> SHIFT], 1);
            atomicAdd(&h[d4.y >> SHIFT], 1);
            atomicAdd(&h[d4.z >> SHIFT], 1);
            atomicAdd(&h[d4.w >> SHIFT], 1);
        }
        int tb = en & ~3;
        if (tb >= s0 && t < en - tb) atomicAdd(&h[dst[tb + t] >> SHIFT], 1);
    }
    __syncthreads();
    for (int i = t; i < NB; i += PTHREADS) {
        int c = h[i];
        base[i] = c ? atomicAdd(&claim[i], c) : 0;
        h[i] = 0;  // reuse as local rank counter
    }
    __syncthreads();
    if (s0 < e) {
        for (int i = s0 + 4 * t; i + 3 < en; i += 4 * PTHREADS) {
            int4 s4 = *(const int4*)(src + i);
            int4 d4 = *(const int4*)(dst + i);
            { int bin = d4.x >> SHIFT; int r = atomicAdd(&h[bin], 1);
              sorted[base[bin] + r] = s4.x | ((d4.x & (BNODES - 1)) << 17); }
            { int bin = d4.y >> SHIFT; int r = atomicAdd(&h[bin], 1);
              sorted[base[bin] + r] = s4.y | ((d4.y & (BNODES - 1)) << 17); }
            { int bin = d4.z >> SHIFT; int r = atomicAdd(&h[bin], 1);
              sorted[base[bin] + r] = s4.z | ((d4.z & (BNODES - 1)) << 17); }
            { int bin = d4.w >> SHIFT; int r = atomicAdd(&h[bin], 1);
              sorted[base[bin] + r] = s4.w | ((d4.w & (BNODES - 1)) << 17); }
        }
        int tb = en & ~3;
        if (tb >= s0 && t < en - tb) {
            int d = dst[tb + t];
            int bin = d >> SHIFT;
            int r = atomicAdd(&h[bin], 1);
            sorted[base[bin] + r] = src[tb + t] | ((d & (BNODES - 1)) << 17);
        }
    }
}

// degree: LDS count per bucket slice, contiguous atomic flush
__global__ __launch_bounds__(EB) void k_deg(const int* __restrict__ offsets,
                                            const int* __restrict__ sorted,
                                            int* deg) {
    __shared__ int cnt[BNODES + 1];
    int t = threadIdx.x;
    for (int i = t; i <= BNODES; i += EB) cnt[i] = 0;
    __syncthreads();
    int b = blockIdx.x / SPLIT, k = blockIdx.x % SPLIT;
    int s = offsets[b], en = offsets[b + 1];
    int c = en - s;
    int chunk = (((c + SPLIT - 1) / SPLIT) + 3) & ~3;
    int vs = s + k * chunk;
    int ve = vs + chunk; if (ve > en) ve = en;
    for (int i = vs + 4 * t; i + 3 < ve; i += 4 * EB) {
        int4 p = *(const int4*)(sorted + i);
        atomicAdd(&cnt[((unsigned)p.x) >> 17], 1);
        atomicAdd(&cnt[((unsigned)p.y) >> 17], 1);
        atomicAdd(&cnt[((unsigned)p.z) >> 17], 1);
        atomicAdd(&cnt[((unsigned)p.w) >> 17], 1);
    }
    __syncthreads();
    for (int i = t; i < BNODES; i += EB) {
        int node = b * BNODES + i;
        if (cnt[i] && node < N_NODES) atomicAdd(&deg[node], cnt[i]);
    }
}

// node: dinv = rsqrt(deg) (in place over deg); u = dinv*x; acc1 = u (self)
__global__ __launch_bounds__(256) void k_prep(const int* degp,
                                              const float* __restrict__ x,
                                              float* dinv, float2* u,
                                              float2* acc1) {
    int i = blockIdx.x * 256 + threadIdx.x;
    if (i < N_NODES) {
        float d = rsqrtf((float)degp[i]);
        dinv[i] = d;
        float2 xv = ((const float2*)x)[i];
        float2 uu = make_float2(d * xv.x, d * xv.y);
        u[i] = uu;
        acc1[i] = uu;
    }
}

// edge slice: gather g[src] into LDS tile, contiguous atomic flush into acc
__global__ __launch_bounds__(EB) void k_agge(const int* __restrict__ offsets,
                                             const int* __restrict__ sorted,
                                             const float2* __restrict__ g,
                                             float* acc) {
    __shared__ float ax[BNODES + 1], ay[BNODES + 1];
    int t = threadIdx.x;
    for (int i = t; i <= BNODES; i += EB) { ax[i] = 0.0f; ay[i] = 0.0f; }
    __syncthreads();
    int b = blockIdx.x / SPLIT, k = blockIdx.x % SPLIT;
    int s = offsets[b], en = offsets[b + 1];
    int c = en - s;
    int chunk = (((c + SPLIT - 1) / SPLIT) + 3) & ~3;
    int vs = s + k * chunk;
    int ve = vs + chunk; if (ve > en) ve = en;
    for (int i = vs + 4 * t; i + 3 < ve; i += 4 * EB) {
        int4 p = *(const int4*)(sorted + i);
        float2 g0 = g[p.x & 0x1FFFF];
        float2 g1 = g[p.y & 0x1FFFF];
        float2 g2 = g[p.z & 0x1FFFF];
        float2 g3 = g[p.w & 0x1FFFF];
        int d0 = ((unsigned)p.x) >> 17, d1 = ((unsigned)p.y) >> 17;
        int d2 = ((unsigned)p.z) >> 17, d3 = ((unsigned)p.w) >> 17;
        atomicAdd(&ax[d0], g0.x); atomicAdd(&ay[d0], g0.y);
        atomicAdd(&ax[d1], g1.x); atomicAdd(&ay[d1], g1.y);
        atomicAdd(&ax[d2], g2.x); atomicAdd(&ay[d2], g2.y);
        atomicAdd(&ax[d3], g3.x); atomicAdd(&ay[d3], g3.y);
    }
    __syncthreads();
    for (int i = t; i < BNODES; i += EB) {
        int node = b * BNODES + i;
        if (node < N_NODES) {
            float vx = ax[i], vy = ay[i];
            if (vx != 0.0f || vy != 0.0f) {
                atomicAdd(&acc[2 * node], vx);
                atomicAdd(&acc[2 * node + 1], vy);
            }
        }
    }
}

// node: a = dinv*acc1; h = relu(W1 a + b1) in regs; v = dinv*(W2 h); acc2 = v
__global__ __launch_bounds__(256) void k_mlp(const float* __restrict__ dinv,
                                             const float2* acc1,
                                             const float* __restrict__ W1,
                                             const float* __restrict__ b1,
                                             const float* __restrict__ W2,
                                             float2* v, float2* acc2) {
    __shared__ float sW1[128], sb1[64], sW2[128];
    int t = threadIdx.x;
    if (t < 128) { sW1[t] = W1[t]; sW2[t] = W2[t]; }
    else if (t < 192) sb1[t - 128] = b1[t - 128];
    __syncthreads();
    int i = blockIdx.x * 256 + t;
    if (i < N_NODES) {
        float dv = dinv[i];
        float2 a2 = acc1[i];
        float a0 = dv * a2.x, a1 = dv * a2.y;
        float y0 = 0.0f, y1 = 0.0f;
#pragma unroll
        for (int j = 0; j < 64; ++j) {
            float h = fmaxf(fmaf(sW1[2 * j], a0,
                            fmaf(sW1[2 * j + 1], a1, sb1[j])), 0.0f);
            y0 = fmaf(sW2[j], h, y0);        // W2[0][j]
            y1 = fmaf(sW2[64 + j], h, y1);   // W2[1][j]
        }
        float2 vv = make_float2(dv * y0, dv * y1);
        v[i] = vv;
        acc2[i] = vv;  // self term; aliases acc1 (read above, per-thread safe)
    }
}

__global__ __launch_bounds__(256) void k_out(const float* __restrict__ dinv,
                                             const float2* __restrict__ acc2,
                                             const float* __restrict__ b2,
                                             float2* out) {
    int i = blockIdx.x * 256 + threadIdx.x;
    if (i < N_NODES) {
        float dv = dinv[i];
        float2 s = acc2[i];
        out[i] = make_float2(fmaf(dv, s.x, b2[0]), fmaf(dv, s.y, b2[1]));
    }
}

extern "C" void kernel_launch(void* const* d_in, const int* in_sizes, int n_in,
                              void* d_out, int out_size, void* d_ws, size_t ws_size,
                              hipStream_t stream) {
    const float* x  = (const float*)d_in[0];
    const int* ei   = (const int*)d_in[1];   // [2,E]: src row then dst row
    const float* W1 = (const float*)d_in[2];
    const float* b1 = (const float*)d_in[3];
    const float* W2 = (const float*)d_in[4];
    const float* b2 = (const float*)d_in[5];

    const int e = in_sizes[1] / 2;
    const int* src = ei;
    const int* dst = ei + e;

    // ws layout (4B units), 16B-aligned sorted base:
    // counts[NB] | offsets[NB+1] | claim[NB] | (pad) | sorted[e+4*NB] |
    // deg/dinv[N] | u[2N] (v aliases u) | acc1[2N] (acc2 aliases acc1)
    int* ws      = (int*)d_ws;
    int* counts  = ws;
    int* offsets = counts + NB;
    int* claim   = offsets + NB + 1;
    int* sorted  = ws + ((NB + NB + 1 + NB + 3) & ~3);   // 16B-aligned
    int sortedCap = (e + 4 * NB + 3) & ~3;
    int* deg     = sorted + sortedCap;
    float* dinv  = (float*)deg;                          // aliases deg
    float2* u    = (float2*)(deg + N_NODES);
    float2* acc1 = u + N_NODES;
    float2* v    = u;                                    // alias: u dead after agg1
    float2* acc2 = acc1;                                 // alias: acc1 dead after mlp

    k_init <<<NBK, 256, 0, stream>>>(counts, deg);
    k_hist <<<PBLOCKS, PTHREADS, 0, stream>>>(dst, counts, e);
    k_scan <<<1, 256, 0, stream>>>(counts, offsets, claim, sorted);
    k_place<<<PBLOCKS, PTHREADS, 0, stream>>>(src, dst, claim, sorted, e);
    k_deg  <<<NB * SPLIT, EB, 0, stream>>>(offsets, sorted, deg);
    k_prep <<<NBK, 256, 0, stream>>>(deg, x, dinv, u, acc1);
    k_agge <<<NB * SPLIT, EB, 0, stream>>>(offsets, sorted, u, (float*)acc1);
    k_mlp  <<<NBK, 256, 0, stream>>>(dinv, acc1, W1, b1, W2, v, acc2);
    k_agge <<<NB * SPLIT, EB, 0, stream>>>(offsets, sorted, v, (float*)acc2);
    k_out  <<<NBK, 256, 0, stream>>>(dinv, acc2, b2, (float2*)d_out);
}